// Round 3
// baseline (100.448 us; speedup 1.0000x reference)
//
#include <hip/hip_runtime.h>

#define NEGV (-1e30f)   // reference's NEG for padded positions

// One block (256 threads) per row. L=512 -> 2 elements/thread.
// Two-pass suffix logsumexp: block max M, then float suffix-sum of exp(x-M).
// Padded positions: x=NEGV -> exp underflows to exactly 0 (== exp(NEG) in ref).
__global__ __launch_bounds__(256) void listnet_row_kernel(
    const float* __restrict__ scores,
    const int*   __restrict__ seqs,
    float2*      __restrict__ part,  // [B] per-row (ll, used)
    int N, int L)
{
    const int b = blockIdx.x;
    const float* srow = scores + (size_t)b * N;
    const int2*  irow = (const int2*)(seqs + (size_t)b * L);

    const int t    = threadIdx.x;   // 0..255
    const int lane = t & 63;
    const int wv   = t >> 6;        // 0..3

    // elements 2t (e0) and 2t+1 (e1), coalesced 8B/lane index load
    int2 ii = irow[t];
    bool v0 = (ii.x != -1), v1 = (ii.y != -1);
    int  c0 = min(max(ii.x, 0), N - 1);
    int  c1 = min(max(ii.y, 0), N - 1);
    float g0 = srow[c0];
    float g1 = srow[c1];
    // torch_sanitize: nan->0, +inf->1e6, -inf->-1e6
    g0 = isnan(g0) ? 0.f : fminf(fmaxf(g0, -1e6f), 1e6f);
    g1 = isnan(g1) ? 0.f : fminf(fmaxf(g1, -1e6f), 1e6f);
    float x0 = v0 ? g0 : NEGV;
    float x1 = v1 ? g1 : NEGV;

    // ---- pass 1: block max (butterfly; all lanes get wave max) ----
    float mx = fmaxf(x0, x1);
    #pragma unroll
    for (int off = 32; off; off >>= 1)
        mx = fmaxf(mx, __shfl_xor(mx, off, 64));
    __shared__ float wmax[4];
    if (lane == 0) wmax[wv] = mx;
    __syncthreads();
    const float M = fmaxf(fmaxf(wmax[0], wmax[1]), fmaxf(wmax[2], wmax[3]));

    // ---- pass 2: suffix sum of exp(x - M) ----
    float e0 = __expf(x0 - M);          // padded -> 0 exactly
    float e1 = __expf(x1 - M);
    float S  = e0 + e1;                 // per-thread pair sum
    // wave-level inclusive suffix sum (lanes [i..63])
    #pragma unroll
    for (int off = 1; off < 64; off <<= 1) {
        float o = __shfl_down(S, off, 64);
        S += (lane + off < 64) ? o : 0.f;
    }
    __shared__ float wtot[4];
    if (lane == 0) wtot[wv] = S;        // whole-wave total
    // suffix strictly after this thread's pair (within wave)
    float Safter = __shfl_down(S, 1, 64);
    if (lane == 63) Safter = 0.f;
    __syncthreads();
    float above = 0.f;                  // totals of higher waves
    if (wv < 3) above += wtot[wv + 1];
    if (wv < 2) above += wtot[wv + 2];
    if (wv < 1) above += wtot[wv + 3];
    const float A = Safter + above;     // suffix strictly after element e1

    // per-element log-denominators (all-positive adds, no cancellation)
    float s1 = e1 + A;
    float s0 = e0 + s1;
    float ll = 0.f;
    if (v1) ll += x1 - (M + __logf(s1));
    if (v0) ll += x0 - (M + __logf(s0));

    // ---- block reduce ll ----
    #pragma unroll
    for (int off = 32; off; off >>= 1)
        ll += __shfl_down(ll, off, 64);
    __shared__ float lsum[4];
    if (lane == 0) lsum[wv] = ll;
    __syncthreads();
    if (t == 0) {
        bool used = (M > -1e29f);       // any valid element in row
        float2 r;
        r.x = used ? (lsum[0] + lsum[1] + lsum[2] + lsum[3]) : 0.f;
        r.y = used ? 1.f : 0.f;
        part[b] = r;
    }
}

// Single-wave reduction over B per-row partials -> scalar loss.
__global__ __launch_bounds__(64) void listnet_finalize_kernel(
    const float2* __restrict__ part, float* __restrict__ out, int B)
{
    const int t = threadIdx.x;          // 0..63, one wave, no LDS needed
    float tot = 0.f, cnt = 0.f;
    for (int i = t; i < B; i += 64) {
        float2 p = part[i];
        tot += p.x;
        cnt += p.y;
    }
    #pragma unroll
    for (int off = 32; off; off >>= 1) {
        tot += __shfl_down(tot, off, 64);
        cnt += __shfl_down(cnt, off, 64);
    }
    if (t == 0)
        out[0] = (cnt > 0.f) ? (-tot / cnt) : 0.f;
}

extern "C" void kernel_launch(void* const* d_in, const int* in_sizes, int n_in,
                              void* d_out, int out_size, void* d_ws, size_t ws_size,
                              hipStream_t stream) {
    const float* scores = (const float*)d_in[0];
    const int*   seqs   = (const int*)d_in[1];
    float*       out    = (float*)d_out;
    float2*      part   = (float2*)d_ws;

    const int L = 512;
    const int B = in_sizes[1] / L;          // 2048
    const int N = in_sizes[0] / B;          // 8192

    listnet_row_kernel<<<B, 256, 0, stream>>>(scores, seqs, part, N, L);
    listnet_finalize_kernel<<<1, 64, 0, stream>>>(part, out, B);
}